// Round 1
// 3513.544 us; speedup vs baseline: 1.3744x; 1.3744x over previous
//
#include <hip/hip_runtime.h>
#include <hip/hip_bf16.h>
#include <math.h>

typedef __hip_bfloat16 bf16;
typedef __attribute__((ext_vector_type(8))) short short8;   // 8 bf16 = 4 VGPRs
typedef __attribute__((ext_vector_type(4))) float f32x4;

#define Bb 4
#define Tt 2048
#define Cc 2048
#define Hh 32
#define Nn 64
#define BT (Bb*Tt)   // 8192
#define Gg 16        // scan chunks per (b,h)
#define Ll 128       // timesteps per chunk (Gg*Ll == Tt)

__device__ __forceinline__ float b2f(bf16 x) { return __bfloat162float(x); }
__device__ __forceinline__ bf16  f2b(float x) { return __float2bfloat16(x); }

// ---------------------------------------------------------------------------
// K0: fp32 -> bf16 weight conversion (for MFMA GEMMs)
// ---------------------------------------------------------------------------
__global__ __launch_bounds__(256) void cvt_kernel(
    const float* __restrict__ in, bf16* __restrict__ out)
{
  int i = blockIdx.x * 256 + threadIdx.x;
  out[i] = f2b(in[i]);
}

// ---------------------------------------------------------------------------
// K1: xm = x + (shift(x) - x) * time_maa_x
// ---------------------------------------------------------------------------
__global__ __launch_bounds__(256) void prep_xm_kernel(
    const float* __restrict__ x, const float* __restrict__ maa_x,
    bf16* __restrict__ xm)
{
  int idx = blockIdx.x * 256 + threadIdx.x;
  int c  = idx & (Cc - 1);
  int bt = idx >> 11;
  int t  = bt & (Tt - 1);
  float xv   = x[idx];
  float prev = (t == 0) ? 0.f : x[idx - Cc];
  xm[idx] = f2b(xv + (prev - xv) * maa_x[c]);
}

// ---------------------------------------------------------------------------
// MFMA GEMM: C[8192,2048] = A[8192,2048](bf16) * B^T, B[2048,2048](bf16,[N,K])
// 128x128 block tile, 4 waves in 2x2, each wave 64x64 via 4x4 16x16x32 MFMAs.
// mode: 0 plain->bf16, 2 silu->bf16, 4 plain->fp32
// ---------------------------------------------------------------------------
#define LDA 40   // padded LDS row (bf16 elems): 20 dwords -> ~2-way conflicts

__global__ __launch_bounds__(256) void mfma_gemm_kernel(
    const bf16* __restrict__ A, const bf16* __restrict__ B,
    bf16* __restrict__ outB, float* __restrict__ outF, int mode)
{
  __shared__ bf16 As[128 * LDA];
  __shared__ bf16 Bs[128 * LDA];
  int tid  = threadIdx.x;
  int lane = tid & 63, wid = tid >> 6;
  int wm = wid & 1, wn = wid >> 1;
  int quad = lane >> 4, l16 = lane & 15;
  size_t rowBase = (size_t)blockIdx.x * 128;
  size_t colBase = (size_t)blockIdx.y * 128;

  f32x4 acc[4][4];
  #pragma unroll
  for (int i = 0; i < 4; ++i)
    #pragma unroll
    for (int j = 0; j < 4; ++j)
      acc[i][j] = (f32x4){0.f, 0.f, 0.f, 0.f};

  for (int k0 = 0; k0 < 2048; k0 += 32) {
    #pragma unroll
    for (int pass = 0; pass < 2; ++pass) {
      int chunk = tid + pass * 256;           // 0..511
      int row = chunk >> 2, kc = (chunk & 3) * 8;
      short8 av = *(const short8*)(A + (rowBase + row) * 2048 + k0 + kc);
      short8 bv = *(const short8*)(B + (colBase + row) * 2048 + k0 + kc);
      *(short8*)(As + row * LDA + kc) = av;
      *(short8*)(Bs + row * LDA + kc) = bv;
    }
    __syncthreads();
    short8 af[4], bf[4];
    #pragma unroll
    for (int i = 0; i < 4; ++i) {
      af[i] = *(const short8*)(As + (wm * 64 + i * 16 + l16) * LDA + quad * 8);
      bf[i] = *(const short8*)(Bs + (wn * 64 + i * 16 + l16) * LDA + quad * 8);
    }
    #pragma unroll
    for (int i = 0; i < 4; ++i)
      #pragma unroll
      for (int j = 0; j < 4; ++j)
        acc[i][j] = __builtin_amdgcn_mfma_f32_16x16x32_bf16(af[i], bf[j], acc[i][j], 0, 0, 0);
    __syncthreads();
  }

  #pragma unroll
  for (int i = 0; i < 4; ++i) {
    #pragma unroll
    for (int j = 0; j < 4; ++j) {
      int gc = colBase + wn * 64 + j * 16 + l16;
      #pragma unroll
      for (int reg = 0; reg < 4; ++reg) {
        int gr = rowBase + wm * 64 + i * 16 + quad * 4 + reg;
        float v = acc[i][j][reg];
        size_t idx = (size_t)gr * 2048 + gc;
        if (mode == 0)      outB[idx] = f2b(v);
        else if (mode == 2) outB[idx] = f2b(v / (1.f + expf(-v)));
        else                outF[idx] = v;
      }
    }
  }
}

// ---------------------------------------------------------------------------
// VALU tiled GEMM for small/skinny shapes. A bf16, B fp32.
// transB: 1 -> B[N,K]; 0 -> B[K,N].
// mode: 1 tanh->bf16, 3 td = bias[n]+acc -> bf16
// ---------------------------------------------------------------------------
#define BM 128
#define BN 128
#define BKk 16

__global__ __launch_bounds__(256) void gemm_kernel(
    const bf16* __restrict__ A, const float* __restrict__ Bm,
    bf16* __restrict__ outB,
    const float* __restrict__ bias,
    int M, int N, int K, int transB, int mode)
{
  __shared__ float As[BKk][BM + 1];
  __shared__ float Bs[BKk][BN + 1];
  int tid = threadIdx.x;
  int rowBase = blockIdx.x * BM;
  int colBase = blockIdx.y * BN;
  int tx = tid & 15, ty = tid >> 4;
  float acc[8][8];
  #pragma unroll
  for (int i = 0; i < 8; ++i)
    #pragma unroll
    for (int j = 0; j < 8; ++j) acc[i][j] = 0.f;

  for (int k0 = 0; k0 < K; k0 += BKk) {
    #pragma unroll
    for (int i = 0; i < 8; ++i) {
      int lin = tid + i * 256;
      int r = lin >> 4, kk = lin & 15;
      int gr = rowBase + r, gk = k0 + kk;
      float val = 0.f;
      if (gr < M && gk < K) val = b2f(A[(size_t)gr * K + gk]);
      As[kk][r] = val;
    }
    #pragma unroll
    for (int i = 0; i < 8; ++i) {
      int lin = tid + i * 256;
      float val = 0.f;
      if (transB) {
        int n = lin >> 4, kk = lin & 15;
        int gn = colBase + n, gk = k0 + kk;
        if (gn < N && gk < K) val = Bm[(size_t)gn * K + gk];
        Bs[kk][n] = val;
      } else {
        int kk = lin >> 7, n = lin & 127;
        int gn = colBase + n, gk = k0 + kk;
        if (gn < N && gk < K) val = Bm[(size_t)gk * N + gn];
        Bs[kk][n] = val;
      }
    }
    __syncthreads();
    #pragma unroll
    for (int kk = 0; kk < BKk; ++kk) {
      float a[8], b[8];
      #pragma unroll
      for (int i = 0; i < 8; ++i) a[i] = As[kk][ty * 8 + i];
      #pragma unroll
      for (int j = 0; j < 8; ++j) b[j] = Bs[kk][tx * 8 + j];
      #pragma unroll
      for (int i = 0; i < 8; ++i)
        #pragma unroll
        for (int j = 0; j < 8; ++j)
          acc[i][j] = fmaf(a[i], b[j], acc[i][j]);
    }
    __syncthreads();
  }
  #pragma unroll
  for (int i = 0; i < 8; ++i) {
    int gr = rowBase + ty * 8 + i;
    if (gr >= M) continue;
    #pragma unroll
    for (int j = 0; j < 8; ++j) {
      int gn = colBase + tx * 8 + j;
      if (gn >= N) continue;
      float v = acc[i][j];
      size_t idx = (size_t)gr * N + gn;
      if (mode == 1)      outB[idx] = f2b(tanhf(v));
      else                outB[idx] = f2b(bias[gn] + v);   // mode 3
    }
  }
}

// ---------------------------------------------------------------------------
// K3: fused 5-way token-shift lerp. m[f] = t5row[f*32:(f+1)*32] @ w2[f]
// ---------------------------------------------------------------------------
__global__ __launch_bounds__(256) void lerp5_kernel(
    const float* __restrict__ x, const bf16* __restrict__ t5,
    const float* __restrict__ w2,   // [160, C]
    const float* __restrict__ maa_w, const float* __restrict__ maa_k,
    const float* __restrict__ maa_v, const float* __restrict__ maa_r,
    const float* __restrict__ maa_g,
    bf16* __restrict__ xd, bf16* __restrict__ xk, bf16* __restrict__ xv_,
    bf16* __restrict__ xr, bf16* __restrict__ xg)
{
  __shared__ float t5s[160];
  int bt   = blockIdx.x >> 3;
  int cblk = blockIdx.x & 7;
  int c = cblk * 256 + threadIdx.x;
  if (threadIdx.x < 160) t5s[threadIdx.x] = b2f(t5[(size_t)bt * 160 + threadIdx.x]);
  __syncthreads();
  int t = bt & (Tt - 1);
  size_t idx = (size_t)bt * Cc + c;
  float xv0  = x[idx];
  float prev = (t == 0) ? 0.f : x[idx - Cc];
  float xx = prev - xv0;
  float m[5];
  #pragma unroll
  for (int f = 0; f < 5; ++f) {
    float s = 0.f;
    #pragma unroll
    for (int e = 0; e < 32; ++e)
      s = fmaf(t5s[f * 32 + e], w2[(size_t)(f * 32 + e) * Cc + c], s);
    m[f] = s;
  }
  xd[idx]  = f2b(xv0 + xx * (maa_w[c] + m[0]));
  xk[idx]  = f2b(xv0 + xx * (maa_k[c] + m[1]));
  xv_[idx] = f2b(xv0 + xx * (maa_v[c] + m[2]));
  xr[idx]  = f2b(xv0 + xx * (maa_r[c] + m[3]));
  xg[idx]  = f2b(xv0 + xx * (maa_g[c] + m[4]));
}

// ---------------------------------------------------------------------------
// K5a: chunked WKV local scan. Grid = B*H*G blocks, one chunk of Ll steps
// per block, starting from ZERO state. Emits per-chunk end state S_local
// [bh*G+c][n][m] and per-channel decay product wp[bh*G+c][n].
// Thread (chunk=tid>>6, m=tid&63) owns s[chunk*16 .. +16)[m].
// Double-buffered LDS, 1 barrier per step.
// ---------------------------------------------------------------------------
__global__ __launch_bounds__(256) void wkv_local_kernel(
    const bf16* __restrict__ k, const bf16* __restrict__ v,
    const bf16* __restrict__ td,
    float* __restrict__ S_local, float* __restrict__ wp)
{
  int bh = blockIdx.x >> 4;          // Gg == 16
  int c  = blockIdx.x & 15;
  int b  = bh >> 5, h = bh & 31;
  int tid = threadIdx.x;
  int m = tid & 63, chunk = tid >> 6;
  __shared__ float kw[2][64][2];     // [buf][ch][{k,w}]
  __shared__ float vsb[2][64];
  float s[16], wpr[16];
  #pragma unroll
  for (int i = 0; i < 16; ++i) { s[i] = 0.f; wpr[i] = 1.f; }
  size_t base = (size_t)b * Tt * Cc + (size_t)(c * Ll) * Cc + (size_t)h * 64;
  for (int t = 0; t < Ll; ++t, base += Cc) {
    int p = t & 1;
    int role = tid >> 6, ch = tid & 63;
    if (role == 0)      kw[p][ch][0] = b2f(k[base + ch]);
    else if (role == 1) kw[p][ch][1] = expf(-expf(b2f(td[base + ch])));
    else if (role == 2) vsb[p][ch]   = b2f(v[base + ch]);
    __syncthreads();
    float vm = vsb[p][m];
    #pragma unroll
    for (int i = 0; i < 16; ++i) {
      float kk = kw[p][chunk * 16 + i][0];
      float ww = kw[p][chunk * 16 + i][1];
      s[i] = fmaf(ww, s[i], kk * vm);
      wpr[i] *= ww;
    }
  }
  size_t sb = ((size_t)blockIdx.x * 64 + chunk * 16) * 64 + m;
  #pragma unroll
  for (int i = 0; i < 16; ++i) S_local[sb + (size_t)i * 64] = s[i];
  if (m == 0) {
    int wb = blockIdx.x * 64 + chunk * 16;
    #pragma unroll
    for (int i = 0; i < 16; ++i) wp[wb + i] = wpr[i];
  }
}

// ---------------------------------------------------------------------------
// K5b: chunk-prefix combine. One thread per (b,h,n,m) state element:
// S_start[c] = running; running = S_local[c] + wp[c][n]*running.
// Fully parallel over 524288 threads; serial only over Gg=16 chunks.
// ---------------------------------------------------------------------------
__global__ __launch_bounds__(256) void wkv_combine_kernel(
    const float* __restrict__ S_local, const float* __restrict__ wp,
    float* __restrict__ S_start)
{
  int idx = blockIdx.x * 256 + threadIdx.x;   // over B*H*N*N
  int m = idx & 63;
  int n = (idx >> 6) & 63;
  int bh = idx >> 12;
  float cur = 0.f;
  #pragma unroll
  for (int c = 0; c < Gg; ++c) {
    size_t sbase = (((size_t)(bh * Gg + c)) * 64 + n) * 64 + m;
    S_start[sbase] = cur;
    cur = fmaf(wp[(bh * Gg + c) * 64 + n], cur, S_local[sbase]);
  }
}

// ---------------------------------------------------------------------------
// K5c: chunked WKV output scan. Same structure as the old serial scan but
// only Ll steps per block, state seeded from S_start. Writes out IN PLACE
// over the td buffer (each block reads td[t] into LDS before writing out[t];
// cross-block (row,col) regions are disjoint).
// ---------------------------------------------------------------------------
__global__ __launch_bounds__(256) void wkv_out_kernel(
    const bf16* __restrict__ r, const bf16* __restrict__ k,
    const bf16* __restrict__ v, const bf16* __restrict__ td,
    const float* __restrict__ u, const float* __restrict__ S_start,
    bf16* __restrict__ out)
{
  int bh = blockIdx.x >> 4;
  int c  = blockIdx.x & 15;
  int b  = bh >> 5, h = bh & 31;
  int tid = threadIdx.x;
  int m = tid & 63, chunk = tid >> 6;
  __shared__ float4 rkw[64];
  __shared__ float vsb[64];
  __shared__ float red[256];
  float s[16], ureg[16];
  size_t sb = ((size_t)blockIdx.x * 64 + chunk * 16) * 64 + m;
  #pragma unroll
  for (int i = 0; i < 16; ++i) {
    s[i]    = S_start[sb + (size_t)i * 64];
    ureg[i] = u[h * 64 + chunk * 16 + i];
  }
  size_t base = (size_t)b * Tt * Cc + (size_t)(c * Ll) * Cc + (size_t)h * 64;
  for (int t = 0; t < Ll; ++t, base += Cc) {
    int role = tid >> 6, ch = tid & 63;
    if (role == 0)      rkw[ch].x = b2f(r[base + ch]);
    else if (role == 1) rkw[ch].y = b2f(k[base + ch]);
    else if (role == 2) rkw[ch].z = expf(-expf(b2f(td[base + ch])));
    else                vsb[ch]   = b2f(v[base + ch]);
    __syncthreads();
    float vm = vsb[m];
    float acc = 0.f;
    #pragma unroll
    for (int i = 0; i < 16; ++i) {
      float4 q = rkw[chunk * 16 + i];
      float kv = q.y * vm;
      acc = fmaf(q.x, fmaf(ureg[i], kv, s[i]), acc);
      s[i] = fmaf(q.z, s[i], kv);
    }
    red[tid] = acc;
    __syncthreads();
    if (tid < 64)
      out[base + tid] = f2b(red[tid] + red[tid + 64] + red[tid + 128] + red[tid + 192]);
  }
}

// ---------------------------------------------------------------------------
// K6: GroupNorm over each head (N=64) + affine + gate with g
// ---------------------------------------------------------------------------
__global__ __launch_bounds__(256) void gn_gate_kernel(
    const bf16* __restrict__ wkv, const bf16* __restrict__ g,
    const float* __restrict__ lnw, const float* __restrict__ lnb,
    bf16* __restrict__ out)
{
  int bt = blockIdx.x;
  int wv = threadIdx.x >> 6, lane = threadIdx.x & 63;
  const float EPS = 6.4e-4f;   // 1e-5 * 8^2
  for (int h = wv; h < Hh; h += 4) {
    size_t base = (size_t)bt * Cc + h * 64;
    float x = b2f(wkv[base + lane]);
    float s = x, s2 = x * x;
    #pragma unroll
    for (int off = 1; off < 64; off <<= 1) {
      s  += __shfl_xor(s, off);
      s2 += __shfl_xor(s2, off);
    }
    float mean = s * (1.f / 64.f);
    float var  = s2 * (1.f / 64.f) - mean * mean;
    float inv  = rsqrtf(var + EPS);
    float normed = (x - mean) * inv * lnw[h * 64 + lane] + lnb[h * 64 + lane];
    out[base + lane] = f2b(normed * b2f(g[base + lane]));
  }
}

// ---------------------------------------------------------------------------
// Workspace: 5 x 33.55 MB bf16 [BT,C] + 4 MB t5 + 4 MB abuf + 5 x 8.39 MB
// bf16 weights ~= 218 MB. d_out (67 MB fp32) lower half = bf16 r-scratch,
// upper half = S_local (33.55 MB fp32). S_start reuses buf0; wp reuses t5buf.
// ---------------------------------------------------------------------------
extern "C" void kernel_launch(void* const* d_in, const int* in_sizes, int n_in,
                              void* d_out, int out_size, void* d_ws, size_t ws_size,
                              hipStream_t stream) {
  const float* hidden = (const float*)d_in[0];
  const float* maa_x  = (const float*)d_in[1];
  const float* maa_w  = (const float*)d_in[2];
  const float* maa_k  = (const float*)d_in[3];
  const float* maa_v  = (const float*)d_in[4];
  const float* maa_r  = (const float*)d_in[5];
  const float* maa_g  = (const float*)d_in[6];
  const float* maa_w1 = (const float*)d_in[7];   // [C,160]
  const float* maa_w2 = (const float*)d_in[8];   // [160,C]
  const float* tdecay = (const float*)d_in[9];   // [C]
  const float* dw1    = (const float*)d_in[10];  // [C,64]
  const float* dw2    = (const float*)d_in[11];  // [64,C]
  const float* faaaa  = (const float*)d_in[12];  // [H,N]
  const float* w_r    = (const float*)d_in[13];
  const float* w_k    = (const float*)d_in[14];
  const float* w_v    = (const float*)d_in[15];
  const float* w_g    = (const float*)d_in[16];
  const float* w_o    = (const float*)d_in[17];
  const float* lnw    = (const float*)d_in[18];
  const float* lnb    = (const float*)d_in[19];
  float* outF = (float*)d_out;
  bf16* rscratch = (bf16*)d_out;

  char* ws = (char*)d_ws;
  const size_t BUF  = (size_t)BT * Cc * sizeof(bf16);   // 33,554,432 B
  const size_t WBUF = (size_t)Cc * Cc * sizeof(bf16);   //  8,388,608 B
  bf16* buf0 = (bf16*)(ws + 0 * BUF);
  bf16* buf1 = (bf16*)(ws + 1 * BUF);
  bf16* buf2 = (bf16*)(ws + 2 * BUF);
  bf16* buf3 = (bf16*)(ws + 3 * BUF);
  bf16* buf4 = (bf16*)(ws + 4 * BUF);
  bf16* t5buf = (bf16*)(ws + 5 * BUF);
  bf16* abuf  = (bf16*)(ws + 5 * BUF + 4 * 1024 * 1024);
  char* wbase = ws + 5 * BUF + 8 * 1024 * 1024;
  bf16* wrb = (bf16*)(wbase + 0 * WBUF);
  bf16* wkb = (bf16*)(wbase + 1 * WBUF);
  bf16* wvb = (bf16*)(wbase + 2 * WBUF);
  bf16* wgb = (bf16*)(wbase + 3 * WBUF);
  bf16* wob = (bf16*)(wbase + 4 * WBUF);

  // scan scratch (no extra workspace): S_local in d_out upper half,
  // S_start in buf0 (free during scan), wp in t5buf (free after lerp5)
  float* slbuf = (float*)((char*)d_out + BUF);   // 33.55 MB fp32
  float* ssbuf = (float*)buf0;                   // 33.55 MB fp32
  float* wpbuf = (float*)t5buf;                  // 512 KB fp32

  dim3 blk(256);
  const int CVT_G = Cc * Cc / 256;   // 16384

  // 0. weight conversions (independent of data pipeline)
  cvt_kernel<<<dim3(CVT_G), blk, 0, stream>>>(w_r, wrb);
  cvt_kernel<<<dim3(CVT_G), blk, 0, stream>>>(w_k, wkb);
  cvt_kernel<<<dim3(CVT_G), blk, 0, stream>>>(w_v, wvb);
  cvt_kernel<<<dim3(CVT_G), blk, 0, stream>>>(w_g, wgb);
  cvt_kernel<<<dim3(CVT_G), blk, 0, stream>>>(w_o, wob);

  // 1. xm -> buf0
  prep_xm_kernel<<<dim3(BT * Cc / 256), blk, 0, stream>>>(hidden, maa_x, buf0);

  // 2. t5 = tanh(xm @ maa_w1): M=8192,N=160,K=2048
  gemm_kernel<<<dim3(64, 2), blk, 0, stream>>>(buf0, maa_w1, t5buf, nullptr,
                                               BT, 160, Cc, 0, 1);

  // 3. fused lerp -> xd(1) xk(2) xv(3) xr(4) xg(0)
  lerp5_kernel<<<dim3(BT * 8), blk, 0, stream>>>(hidden, t5buf, maa_w2,
      maa_w, maa_k, maa_v, maa_r, maa_g, buf1, buf2, buf3, buf4, buf0);

  // 4. decay: a = tanh(xd @ dw1) [8192,64]; td = tdecay + a @ dw2 -> buf1
  gemm_kernel<<<dim3(64, 1), blk, 0, stream>>>(buf1, dw1, abuf, nullptr,
                                               BT, 64, Cc, 0, 1);
  gemm_kernel<<<dim3(64, 16), blk, 0, stream>>>(abuf, dw2, buf1, tdecay,
                                                BT, Cc, 64, 0, 3);

  // 5. projections (MFMA): r->rscratch, k->buf4, v->buf2, g(silu)->buf3
  mfma_gemm_kernel<<<dim3(64, 16), blk, 0, stream>>>(buf4, wrb, rscratch, nullptr, 0);
  mfma_gemm_kernel<<<dim3(64, 16), blk, 0, stream>>>(buf2, wkb, buf4, nullptr, 0);
  mfma_gemm_kernel<<<dim3(64, 16), blk, 0, stream>>>(buf3, wvb, buf2, nullptr, 0);
  mfma_gemm_kernel<<<dim3(64, 16), blk, 0, stream>>>(buf0, wgb, buf3, nullptr, 2);

  // 6. chunked WKV scan: r=rscratch, k=buf4, v=buf2, td=buf1 -> out over buf1
  wkv_local_kernel<<<dim3(Bb * Hh * Gg), blk, 0, stream>>>(buf4, buf2, buf1,
                                                           slbuf, wpbuf);
  wkv_combine_kernel<<<dim3(Bb * Hh * Nn * Nn / 256), blk, 0, stream>>>(
      slbuf, wpbuf, ssbuf);
  wkv_out_kernel<<<dim3(Bb * Hh * Gg), blk, 0, stream>>>(rscratch, buf4, buf2,
      buf1, faaaa, ssbuf, buf1);

  // 7. GroupNorm + gate -> buf4 (wkv out now lives in buf1)
  gn_gate_kernel<<<dim3(BT), blk, 0, stream>>>(buf1, buf3, lnw, lnb, buf4);

  // 8. final projection (MFMA) -> d_out fp32
  mfma_gemm_kernel<<<dim3(64, 16), blk, 0, stream>>>(buf4, wob, nullptr, outF, 4);
}

// Round 3
// 1908.730 us; speedup vs baseline: 2.5300x; 1.8408x over previous
//
#include <hip/hip_runtime.h>
#include <hip/hip_bf16.h>
#include <math.h>

typedef __hip_bfloat16 bf16;
typedef __attribute__((ext_vector_type(8))) short short8;   // 8 bf16 = 4 VGPRs
typedef __attribute__((ext_vector_type(4))) float f32x4;

#define Bb 4
#define Tt 2048
#define Cc 2048
#define Hh 32
#define Nn 64
#define BT (Bb*Tt)   // 8192
#define Gg 16        // scan chunks per (b,h)
#define Ll 128       // timesteps per chunk (Gg*Ll == Tt)
#define SPLITK 8     // K-split for skinny MFMA gemms

__device__ __forceinline__ float b2f(bf16 x) { return __bfloat162float(x); }
__device__ __forceinline__ bf16  f2b(float x) { return __float2bfloat16(x); }

// ---------------------------------------------------------------------------
// K0: fp32 -> bf16 weight conversion (for MFMA GEMMs)
// ---------------------------------------------------------------------------
__global__ __launch_bounds__(256) void cvt_kernel(
    const float* __restrict__ in, bf16* __restrict__ out)
{
  int i = blockIdx.x * 256 + threadIdx.x;
  out[i] = f2b(in[i]);
}

// ---------------------------------------------------------------------------
// K0b: fp32 [K,N] -> bf16 hi/lo [N,K] transpose-convert (K == 2048 fixed).
// hi = bf16(w); lo = bf16(w - hi). Two-MFMA accumulation recovers ~fp32 B.
// ---------------------------------------------------------------------------
__global__ __launch_bounds__(256) void cvt_t2_kernel(
    const float* __restrict__ in, bf16* __restrict__ hi, bf16* __restrict__ lo,
    int N)
{
  int idx = blockIdx.x * 256 + threadIdx.x;   // over N*2048
  int n = idx >> 11, k = idx & 2047;
  float v = in[(size_t)k * N + n];
  bf16 h = f2b(v);
  hi[idx] = h;
  lo[idx] = f2b(v - b2f(h));
}

// ---------------------------------------------------------------------------
// K1: xm = x + (shift(x) - x) * time_maa_x
// ---------------------------------------------------------------------------
__global__ __launch_bounds__(256) void prep_xm_kernel(
    const float* __restrict__ x, const float* __restrict__ maa_x,
    bf16* __restrict__ xm)
{
  int idx = blockIdx.x * 256 + threadIdx.x;
  int c  = idx & (Cc - 1);
  int bt = idx >> 11;
  int t  = bt & (Tt - 1);
  float xv   = x[idx];
  float prev = (t == 0) ? 0.f : x[idx - Cc];
  xm[idx] = f2b(xv + (prev - xv) * maa_x[c]);
}

// ---------------------------------------------------------------------------
// MFMA GEMM: C[8192,2048] = A[8192,2048](bf16) * B^T, B[2048,2048](bf16,[N,K])
// 128x128 block tile, 4 waves in 2x2, each wave 64x64 via 4x4 16x16x32 MFMAs.
// mode: 0 plain->bf16, 2 silu->bf16, 4 plain->fp32
// ---------------------------------------------------------------------------
#define LDA 40   // padded LDS row (bf16 elems): 20 dwords -> ~2-way conflicts

__global__ __launch_bounds__(256) void mfma_gemm_kernel(
    const bf16* __restrict__ A, const bf16* __restrict__ B,
    bf16* __restrict__ outB, float* __restrict__ outF, int mode)
{
  __shared__ bf16 As[128 * LDA];
  __shared__ bf16 Bs[128 * LDA];
  int tid  = threadIdx.x;
  int lane = tid & 63, wid = tid >> 6;
  int wm = wid & 1, wn = wid >> 1;
  int quad = lane >> 4, l16 = lane & 15;
  size_t rowBase = (size_t)blockIdx.x * 128;
  size_t colBase = (size_t)blockIdx.y * 128;

  f32x4 acc[4][4];
  #pragma unroll
  for (int i = 0; i < 4; ++i)
    #pragma unroll
    for (int j = 0; j < 4; ++j)
      acc[i][j] = (f32x4){0.f, 0.f, 0.f, 0.f};

  for (int k0 = 0; k0 < 2048; k0 += 32) {
    #pragma unroll
    for (int pass = 0; pass < 2; ++pass) {
      int chunk = tid + pass * 256;           // 0..511
      int row = chunk >> 2, kc = (chunk & 3) * 8;
      short8 av = *(const short8*)(A + (rowBase + row) * 2048 + k0 + kc);
      short8 bv = *(const short8*)(B + (colBase + row) * 2048 + k0 + kc);
      *(short8*)(As + row * LDA + kc) = av;
      *(short8*)(Bs + row * LDA + kc) = bv;
    }
    __syncthreads();
    short8 af[4], bf[4];
    #pragma unroll
    for (int i = 0; i < 4; ++i) {
      af[i] = *(const short8*)(As + (wm * 64 + i * 16 + l16) * LDA + quad * 8);
      bf[i] = *(const short8*)(Bs + (wn * 64 + i * 16 + l16) * LDA + quad * 8);
    }
    #pragma unroll
    for (int i = 0; i < 4; ++i)
      #pragma unroll
      for (int j = 0; j < 4; ++j)
        acc[i][j] = __builtin_amdgcn_mfma_f32_16x16x32_bf16(af[i], bf[j], acc[i][j], 0, 0, 0);
    __syncthreads();
  }

  #pragma unroll
  for (int i = 0; i < 4; ++i) {
    #pragma unroll
    for (int j = 0; j < 4; ++j) {
      int gc = colBase + wn * 64 + j * 16 + l16;
      #pragma unroll
      for (int reg = 0; reg < 4; ++reg) {
        int gr = rowBase + wm * 64 + i * 16 + quad * 4 + reg;
        float v = acc[i][j][reg];
        size_t idx = (size_t)gr * 2048 + gc;
        if (mode == 0)      outB[idx] = f2b(v);
        else if (mode == 2) outB[idx] = f2b(v / (1.f + expf(-v)));
        else                outF[idx] = v;
      }
    }
  }
}

// ---------------------------------------------------------------------------
// Skinny MFMA GEMM with split-K and hi/lo B compensation:
// C_partial[kseg][8192][N] = A_seg @ (Bhi+Blo)_seg^T.
// A [8192,2048] bf16; Bt_hi/Bt_lo [N,2048] bf16. N = NF*16 (<=160).
// Grid (128 row-blocks, SPLITK). 4 waves; wave w owns rows w*16..+16.
// Deterministic fp32 partials (no atomics); reduce_tanh sums + activates.
// ---------------------------------------------------------------------------
template<int NF>
__global__ __launch_bounds__(256) void mfma_skinny_kernel(
    const bf16* __restrict__ A, const bf16* __restrict__ Bt_hi,
    const bf16* __restrict__ Bt_lo,
    float* __restrict__ partial, int kseg_len)
{
  constexpr int N = NF * 16;
  __shared__ bf16 As[64 * LDA];
  __shared__ bf16 Bs[2 * N * LDA];   // rows 0..N-1 hi, N..2N-1 lo
  int tid = threadIdx.x;
  int lane = tid & 63, w = tid >> 6;
  int quad = lane >> 4, l16 = lane & 15;
  int rowBase = blockIdx.x * 64;
  int kbeg = blockIdx.y * kseg_len;

  f32x4 acc[NF];
  #pragma unroll
  for (int f = 0; f < NF; ++f) acc[f] = (f32x4){0.f, 0.f, 0.f, 0.f};

  for (int k0 = kbeg; k0 < kbeg + kseg_len; k0 += 32) {
    // stage A 64x32 (256 threads x 8 elems)
    {
      int row = tid >> 2, kc = (tid & 3) * 8;
      *(short8*)(As + row * LDA + kc) =
          *(const short8*)(A + (size_t)(rowBase + row) * 2048 + k0 + kc);
    }
    // stage B hi and lo, N x 32 each
    for (int c = tid; c < N * 8; c += 256) {
      int half = c >= N * 4;
      int cc = c - half * N * 4;
      int row = cc >> 2, kc = (cc & 3) * 8;
      const bf16* src = half ? Bt_lo : Bt_hi;
      *(short8*)(Bs + (half * N + row) * LDA + kc) =
          *(const short8*)(src + (size_t)row * 2048 + k0 + kc);
    }
    __syncthreads();
    short8 af = *(const short8*)(As + (w * 16 + l16) * LDA + quad * 8);
    #pragma unroll
    for (int f = 0; f < NF; ++f) {
      short8 bh = *(const short8*)(Bs + (f * 16 + l16) * LDA + quad * 8);
      short8 bl = *(const short8*)(Bs + ((N + f * 16 + l16)) * LDA + quad * 8);
      acc[f] = __builtin_amdgcn_mfma_f32_16x16x32_bf16(af, bh, acc[f], 0, 0, 0);
      acc[f] = __builtin_amdgcn_mfma_f32_16x16x32_bf16(af, bl, acc[f], 0, 0, 0);
    }
    __syncthreads();
  }

  #pragma unroll
  for (int f = 0; f < NF; ++f) {
    int gc = f * 16 + l16;
    #pragma unroll
    for (int reg = 0; reg < 4; ++reg) {
      int gr = rowBase + w * 16 + quad * 4 + reg;
      partial[((size_t)blockIdx.y * 8192 + gr) * N + gc] = acc[f][reg];
    }
  }
}

// sum SPLITK partials + tanh -> bf16
__global__ __launch_bounds__(256) void reduce_tanh_kernel(
    const float* __restrict__ partial, bf16* __restrict__ out, int MN)
{
  int idx = blockIdx.x * 256 + threadIdx.x;
  float s = 0.f;
  #pragma unroll
  for (int j = 0; j < SPLITK; ++j) s += partial[(size_t)j * MN + idx];
  out[idx] = f2b(tanhf(s));
}

// ---------------------------------------------------------------------------
// VALU tiled GEMM (still used for td: M=8192,N=2048,K=64). A bf16, B fp32.
// transB: 1 -> B[N,K]; 0 -> B[K,N].
// mode: 1 tanh->bf16, 3 td = bias[n]+acc -> bf16
// ---------------------------------------------------------------------------
#define BM 128
#define BN 128
#define BKk 16

__global__ __launch_bounds__(256) void gemm_kernel(
    const bf16* __restrict__ A, const float* __restrict__ Bm,
    bf16* __restrict__ outB,
    const float* __restrict__ bias,
    int M, int N, int K, int transB, int mode)
{
  __shared__ float As[BKk][BM + 1];
  __shared__ float Bs[BKk][BN + 1];
  int tid = threadIdx.x;
  int rowBase = blockIdx.x * BM;
  int colBase = blockIdx.y * BN;
  int tx = tid & 15, ty = tid >> 4;
  float acc[8][8];
  #pragma unroll
  for (int i = 0; i < 8; ++i)
    #pragma unroll
    for (int j = 0; j < 8; ++j) acc[i][j] = 0.f;

  for (int k0 = 0; k0 < K; k0 += BKk) {
    #pragma unroll
    for (int i = 0; i < 8; ++i) {
      int lin = tid + i * 256;
      int r = lin >> 4, kk = lin & 15;
      int gr = rowBase + r, gk = k0 + kk;
      float val = 0.f;
      if (gr < M && gk < K) val = b2f(A[(size_t)gr * K + gk]);
      As[kk][r] = val;
    }
    #pragma unroll
    for (int i = 0; i < 8; ++i) {
      int lin = tid + i * 256;
      float val = 0.f;
      if (transB) {
        int n = lin >> 4, kk = lin & 15;
        int gn = colBase + n, gk = k0 + kk;
        if (gn < N && gk < K) val = Bm[(size_t)gn * K + gk];
        Bs[kk][n] = val;
      } else {
        int kk = lin >> 7, n = lin & 127;
        int gn = colBase + n, gk = k0 + kk;
        if (gn < N && gk < K) val = Bm[(size_t)gk * N + gn];
        Bs[kk][n] = val;
      }
    }
    __syncthreads();
    #pragma unroll
    for (int kk = 0; kk < BKk; ++kk) {
      float a[8], b[8];
      #pragma unroll
      for (int i = 0; i < 8; ++i) a[i] = As[kk][ty * 8 + i];
      #pragma unroll
      for (int j = 0; j < 8; ++j) b[j] = Bs[kk][tx * 8 + j];
      #pragma unroll
      for (int i = 0; i < 8; ++i)
        #pragma unroll
        for (int j = 0; j < 8; ++j)
          acc[i][j] = fmaf(a[i], b[j], acc[i][j]);
    }
    __syncthreads();
  }
  #pragma unroll
  for (int i = 0; i < 8; ++i) {
    int gr = rowBase + ty * 8 + i;
    if (gr >= M) continue;
    #pragma unroll
    for (int j = 0; j < 8; ++j) {
      int gn = colBase + tx * 8 + j;
      if (gn >= N) continue;
      float v = acc[i][j];
      size_t idx = (size_t)gr * N + gn;
      if (mode == 1)      outB[idx] = f2b(tanhf(v));
      else                outB[idx] = f2b(bias[gn] + v);   // mode 3
    }
  }
}

// ---------------------------------------------------------------------------
// K3: fused 5-way token-shift lerp. m[f] = t5row[f*32:(f+1)*32] @ w2[f]
// ---------------------------------------------------------------------------
__global__ __launch_bounds__(256) void lerp5_kernel(
    const float* __restrict__ x, const bf16* __restrict__ t5,
    const float* __restrict__ w2,   // [160, C]
    const float* __restrict__ maa_w, const float* __restrict__ maa_k,
    const float* __restrict__ maa_v, const float* __restrict__ maa_r,
    const float* __restrict__ maa_g,
    bf16* __restrict__ xd, bf16* __restrict__ xk, bf16* __restrict__ xv_,
    bf16* __restrict__ xr, bf16* __restrict__ xg)
{
  __shared__ float t5s[160];
  int bt   = blockIdx.x >> 3;
  int cblk = blockIdx.x & 7;
  int c = cblk * 256 + threadIdx.x;
  if (threadIdx.x < 160) t5s[threadIdx.x] = b2f(t5[(size_t)bt * 160 + threadIdx.x]);
  __syncthreads();
  int t = bt & (Tt - 1);
  size_t idx = (size_t)bt * Cc + c;
  float xv0  = x[idx];
  float prev = (t == 0) ? 0.f : x[idx - Cc];
  float xx = prev - xv0;
  float m[5];
  #pragma unroll
  for (int f = 0; f < 5; ++f) {
    float s = 0.f;
    #pragma unroll
    for (int e = 0; e < 32; ++e)
      s = fmaf(t5s[f * 32 + e], w2[(size_t)(f * 32 + e) * Cc + c], s);
    m[f] = s;
  }
  xd[idx]  = f2b(xv0 + xx * (maa_w[c] + m[0]));
  xk[idx]  = f2b(xv0 + xx * (maa_k[c] + m[1]));
  xv_[idx] = f2b(xv0 + xx * (maa_v[c] + m[2]));
  xr[idx]  = f2b(xv0 + xx * (maa_r[c] + m[3]));
  xg[idx]  = f2b(xv0 + xx * (maa_g[c] + m[4]));
}

// ---------------------------------------------------------------------------
// K5a: chunked WKV local scan. Grid = B*H*G.
// ---------------------------------------------------------------------------
__global__ __launch_bounds__(256) void wkv_local_kernel(
    const bf16* __restrict__ k, const bf16* __restrict__ v,
    const bf16* __restrict__ td,
    float* __restrict__ S_local, float* __restrict__ wp)
{
  int bh = blockIdx.x >> 4;          // Gg == 16
  int c  = blockIdx.x & 15;
  int b  = bh >> 5, h = bh & 31;
  int tid = threadIdx.x;
  int m = tid & 63, chunk = tid >> 6;
  __shared__ float kw[2][64][2];     // [buf][ch][{k,w}]
  __shared__ float vsb[2][64];
  float s[16], wpr[16];
  #pragma unroll
  for (int i = 0; i < 16; ++i) { s[i] = 0.f; wpr[i] = 1.f; }
  size_t base = (size_t)b * Tt * Cc + (size_t)(c * Ll) * Cc + (size_t)h * 64;
  for (int t = 0; t < Ll; ++t, base += Cc) {
    int p = t & 1;
    int role = tid >> 6, ch = tid & 63;
    if (role == 0)      kw[p][ch][0] = b2f(k[base + ch]);
    else if (role == 1) kw[p][ch][1] = expf(-expf(b2f(td[base + ch])));
    else if (role == 2) vsb[p][ch]   = b2f(v[base + ch]);
    __syncthreads();
    float vm = vsb[p][m];
    #pragma unroll
    for (int i = 0; i < 16; ++i) {
      float kk = kw[p][chunk * 16 + i][0];
      float ww = kw[p][chunk * 16 + i][1];
      s[i] = fmaf(ww, s[i], kk * vm);
      wpr[i] *= ww;
    }
  }
  size_t sb = ((size_t)blockIdx.x * 64 + chunk * 16) * 64 + m;
  #pragma unroll
  for (int i = 0; i < 16; ++i) S_local[sb + (size_t)i * 64] = s[i];
  if (m == 0) {
    int wb = blockIdx.x * 64 + chunk * 16;
    #pragma unroll
    for (int i = 0; i < 16; ++i) wp[wb + i] = wpr[i];
  }
}

// ---------------------------------------------------------------------------
// K5b: chunk-prefix combine over Gg=16 chunks, parallel over (b,h,n,m).
// ---------------------------------------------------------------------------
__global__ __launch_bounds__(256) void wkv_combine_kernel(
    const float* __restrict__ S_local, const float* __restrict__ wp,
    float* __restrict__ S_start)
{
  int idx = blockIdx.x * 256 + threadIdx.x;   // over B*H*N*N
  int m = idx & 63;
  int n = (idx >> 6) & 63;
  int bh = idx >> 12;
  float cur = 0.f;
  #pragma unroll
  for (int c = 0; c < Gg; ++c) {
    size_t sbase = (((size_t)(bh * Gg + c)) * 64 + n) * 64 + m;
    S_start[sbase] = cur;
    cur = fmaf(wp[(bh * Gg + c) * 64 + n], cur, S_local[sbase]);
  }
}

// ---------------------------------------------------------------------------
// K5c: chunked WKV output scan, seeded from S_start; writes in place over td.
// ---------------------------------------------------------------------------
__global__ __launch_bounds__(256) void wkv_out_kernel(
    const bf16* __restrict__ r, const bf16* __restrict__ k,
    const bf16* __restrict__ v, const bf16* __restrict__ td,
    const float* __restrict__ u, const float* __restrict__ S_start,
    bf16* __restrict__ out)
{
  int bh = blockIdx.x >> 4;
  int c  = blockIdx.x & 15;
  int b  = bh >> 5, h = bh & 31;
  int tid = threadIdx.x;
  int m = tid & 63, chunk = tid >> 6;
  __shared__ float4 rkw[64];
  __shared__ float vsb[64];
  __shared__ float red[256];
  float s[16], ureg[16];
  size_t sb = ((size_t)blockIdx.x * 64 + chunk * 16) * 64 + m;
  #pragma unroll
  for (int i = 0; i < 16; ++i) {
    s[i]    = S_start[sb + (size_t)i * 64];
    ureg[i] = u[h * 64 + chunk * 16 + i];
  }
  size_t base = (size_t)b * Tt * Cc + (size_t)(c * Ll) * Cc + (size_t)h * 64;
  for (int t = 0; t < Ll; ++t, base += Cc) {
    int role = tid >> 6, ch = tid & 63;
    if (role == 0)      rkw[ch].x = b2f(r[base + ch]);
    else if (role == 1) rkw[ch].y = b2f(k[base + ch]);
    else if (role == 2) rkw[ch].z = expf(-expf(b2f(td[base + ch])));
    else                vsb[ch]   = b2f(v[base + ch]);
    __syncthreads();
    float vm = vsb[m];
    float acc = 0.f;
    #pragma unroll
    for (int i = 0; i < 16; ++i) {
      float4 q = rkw[chunk * 16 + i];
      float kv = q.y * vm;
      acc = fmaf(q.x, fmaf(ureg[i], kv, s[i]), acc);
      s[i] = fmaf(q.z, s[i], kv);
    }
    red[tid] = acc;
    __syncthreads();
    if (tid < 64)
      out[base + tid] = f2b(red[tid] + red[tid + 64] + red[tid + 128] + red[tid + 192]);
  }
}

// ---------------------------------------------------------------------------
// K6: GroupNorm over each head (N=64) + affine + gate with g
// ---------------------------------------------------------------------------
__global__ __launch_bounds__(256) void gn_gate_kernel(
    const bf16* __restrict__ wkv, const bf16* __restrict__ g,
    const float* __restrict__ lnw, const float* __restrict__ lnb,
    bf16* __restrict__ out)
{
  int bt = blockIdx.x;
  int wv = threadIdx.x >> 6, lane = threadIdx.x & 63;
  const float EPS = 6.4e-4f;   // 1e-5 * 8^2
  for (int h = wv; h < Hh; h += 4) {
    size_t base = (size_t)bt * Cc + h * 64;
    float x = b2f(wkv[base + lane]);
    float s = x, s2 = x * x;
    #pragma unroll
    for (int off = 1; off < 64; off <<= 1) {
      s  += __shfl_xor(s, off);
      s2 += __shfl_xor(s2, off);
    }
    float mean = s * (1.f / 64.f);
    float var  = s2 * (1.f / 64.f) - mean * mean;
    float inv  = rsqrtf(var + EPS);
    float normed = (x - mean) * inv * lnw[h * 64 + lane] + lnb[h * 64 + lane];
    out[base + lane] = f2b(normed * b2f(g[base + lane]));
  }
}

// ---------------------------------------------------------------------------
// Workspace map: 5 x 33.55 MB bf16 [BT,C] + 8 MB small-region + 5 x 8.39 MB
// bf16 weights ~= 218 MB. Small-region layout (offsets from ws+5*BUF):
//   +0      t5buf (2.5 MB bf16), doubles as wp (512 KB fp32) at scan time
//   +4 MB   abuf (1 MB bf16)
//   +5 MB   w1t_hi (640 KB), +5.75 MB w1t_lo (640 KB)
//   +6.5 MB dw1t_hi (256 KB), +6.75 MB dw1t_lo (256 KB)
// d_out (67 MB): skinny-gemm fp32 partials (stages 2,4), then lower half =
// bf16 r-scratch + upper half = S_local. S_start reuses buf0.
// ---------------------------------------------------------------------------
extern "C" void kernel_launch(void* const* d_in, const int* in_sizes, int n_in,
                              void* d_out, int out_size, void* d_ws, size_t ws_size,
                              hipStream_t stream) {
  const float* hidden = (const float*)d_in[0];
  const float* maa_x  = (const float*)d_in[1];
  const float* maa_w  = (const float*)d_in[2];
  const float* maa_k  = (const float*)d_in[3];
  const float* maa_v  = (const float*)d_in[4];
  const float* maa_r  = (const float*)d_in[5];
  const float* maa_g  = (const float*)d_in[6];
  const float* maa_w1 = (const float*)d_in[7];   // [C,160]
  const float* maa_w2 = (const float*)d_in[8];   // [160,C]
  const float* tdecay = (const float*)d_in[9];   // [C]
  const float* dw1    = (const float*)d_in[10];  // [C,64]
  const float* dw2    = (const float*)d_in[11];  // [64,C]
  const float* faaaa  = (const float*)d_in[12];  // [H,N]
  const float* w_r    = (const float*)d_in[13];
  const float* w_k    = (const float*)d_in[14];
  const float* w_v    = (const float*)d_in[15];
  const float* w_g    = (const float*)d_in[16];
  const float* w_o    = (const float*)d_in[17];
  const float* lnw    = (const float*)d_in[18];
  const float* lnb    = (const float*)d_in[19];
  float* outF = (float*)d_out;
  bf16* rscratch = (bf16*)d_out;

  char* ws = (char*)d_ws;
  const size_t BUF  = (size_t)BT * Cc * sizeof(bf16);   // 33,554,432 B
  const size_t WBUF = (size_t)Cc * Cc * sizeof(bf16);   //  8,388,608 B
  const size_t MB = 1024 * 1024;
  bf16* buf0 = (bf16*)(ws + 0 * BUF);
  bf16* buf1 = (bf16*)(ws + 1 * BUF);
  bf16* buf2 = (bf16*)(ws + 2 * BUF);
  bf16* buf3 = (bf16*)(ws + 3 * BUF);
  bf16* buf4 = (bf16*)(ws + 4 * BUF);
  char* small = ws + 5 * BUF;
  bf16* t5buf   = (bf16*)(small + 0);
  bf16* abuf    = (bf16*)(small + 4 * MB);
  bf16* w1t_hi  = (bf16*)(small + 5 * MB);
  bf16* w1t_lo  = (bf16*)(small + 5 * MB + 768 * 1024);
  bf16* dw1t_hi = (bf16*)(small + 6 * MB + 512 * 1024);
  bf16* dw1t_lo = (bf16*)(small + 6 * MB + 768 * 1024);
  char* wbase = small + 8 * MB;
  bf16* wrb = (bf16*)(wbase + 0 * WBUF);
  bf16* wkb = (bf16*)(wbase + 1 * WBUF);
  bf16* wvb = (bf16*)(wbase + 2 * WBUF);
  bf16* wgb = (bf16*)(wbase + 3 * WBUF);
  bf16* wob = (bf16*)(wbase + 4 * WBUF);

  // scan scratch: S_local in d_out upper half, S_start in buf0, wp in t5buf
  float* slbuf = (float*)((char*)d_out + BUF);   // 33.55 MB fp32
  float* ssbuf = (float*)buf0;                   // 33.55 MB fp32
  float* wpbuf = (float*)t5buf;                  // 512 KB fp32
  // skinny-gemm partial scratch: full d_out (free until stage 5)
  float* pbuf  = (float*)d_out;                  // up to 41.9 MB fp32

  dim3 blk(256);
  const int CVT_G = Cc * Cc / 256;   // 16384

  // 0. weight conversions (independent of data pipeline)
  cvt_kernel<<<dim3(CVT_G), blk, 0, stream>>>(w_r, wrb);
  cvt_kernel<<<dim3(CVT_G), blk, 0, stream>>>(w_k, wkb);
  cvt_kernel<<<dim3(CVT_G), blk, 0, stream>>>(w_v, wvb);
  cvt_kernel<<<dim3(CVT_G), blk, 0, stream>>>(w_g, wgb);
  cvt_kernel<<<dim3(CVT_G), blk, 0, stream>>>(w_o, wob);
  cvt_t2_kernel<<<dim3(160 * Cc / 256), blk, 0, stream>>>(maa_w1, w1t_hi, w1t_lo, 160);
  cvt_t2_kernel<<<dim3(64 * Cc / 256), blk, 0, stream>>>(dw1, dw1t_hi, dw1t_lo, 64);

  // 1. xm -> buf0
  prep_xm_kernel<<<dim3(BT * Cc / 256), blk, 0, stream>>>(hidden, maa_x, buf0);

  // 2. t5 = tanh(xm @ maa_w1): M=8192,N=160,K=2048 via split-K MFMA (hi/lo)
  mfma_skinny_kernel<10><<<dim3(128, SPLITK), blk, 0, stream>>>(
      buf0, w1t_hi, w1t_lo, pbuf, 2048 / SPLITK);
  reduce_tanh_kernel<<<dim3(BT * 160 / 256), blk, 0, stream>>>(pbuf, t5buf,
                                                               BT * 160);

  // 3. fused lerp -> xd(1) xk(2) xv(3) xr(4) xg(0)
  lerp5_kernel<<<dim3(BT * 8), blk, 0, stream>>>(hidden, t5buf, maa_w2,
      maa_w, maa_k, maa_v, maa_r, maa_g, buf1, buf2, buf3, buf4, buf0);

  // 4. decay: a = tanh(xd @ dw1) [8192,64] via split-K MFMA (hi/lo);
  //    td = tdecay + a @ dw2 -> buf1 (VALU gemm, K=64)
  mfma_skinny_kernel<4><<<dim3(128, SPLITK), blk, 0, stream>>>(
      buf1, dw1t_hi, dw1t_lo, pbuf, 2048 / SPLITK);
  reduce_tanh_kernel<<<dim3(BT * 64 / 256), blk, 0, stream>>>(pbuf, abuf,
                                                              BT * 64);
  gemm_kernel<<<dim3(64, 16), blk, 0, stream>>>(abuf, dw2, buf1, tdecay,
                                                BT, Cc, 64, 0, 3);

  // 5. projections (MFMA): r->rscratch, k->buf4, v->buf2, g(silu)->buf3
  mfma_gemm_kernel<<<dim3(64, 16), blk, 0, stream>>>(buf4, wrb, rscratch, nullptr, 0);
  mfma_gemm_kernel<<<dim3(64, 16), blk, 0, stream>>>(buf2, wkb, buf4, nullptr, 0);
  mfma_gemm_kernel<<<dim3(64, 16), blk, 0, stream>>>(buf3, wvb, buf2, nullptr, 0);
  mfma_gemm_kernel<<<dim3(64, 16), blk, 0, stream>>>(buf0, wgb, buf3, nullptr, 2);

  // 6. chunked WKV scan: r=rscratch, k=buf4, v=buf2, td=buf1 -> out over buf1
  wkv_local_kernel<<<dim3(Bb * Hh * Gg), blk, 0, stream>>>(buf4, buf2, buf1,
                                                           slbuf, wpbuf);
  wkv_combine_kernel<<<dim3(Bb * Hh * Nn * Nn / 256), blk, 0, stream>>>(
      slbuf, wpbuf, ssbuf);
  wkv_out_kernel<<<dim3(Bb * Hh * Gg), blk, 0, stream>>>(rscratch, buf4, buf2,
      buf1, faaaa, ssbuf, buf1);

  // 7. GroupNorm + gate -> buf4 (wkv out now lives in buf1)
  gn_gate_kernel<<<dim3(BT), blk, 0, stream>>>(buf1, buf3, lnw, lnb, buf4);

  // 8. final projection (MFMA) -> d_out fp32
  mfma_gemm_kernel<<<dim3(64, 16), blk, 0, stream>>>(buf4, wob, nullptr, outF, 4);
}

// Round 4
// 1829.929 us; speedup vs baseline: 2.6389x; 1.0431x over previous
//
#include <hip/hip_runtime.h>
#include <hip/hip_bf16.h>
#include <math.h>

typedef __hip_bfloat16 bf16;
typedef __attribute__((ext_vector_type(8))) short short8;   // 8 bf16 = 4 VGPRs
typedef __attribute__((ext_vector_type(4))) float f32x4;

#define Bb 4
#define Tt 2048
#define Cc 2048
#define Hh 32
#define Nn 64
#define BT (Bb*Tt)   // 8192
#define Gg 16        // scan chunks per (b,h)
#define Ll 128       // timesteps per chunk (Gg*Ll == Tt)
#define SPLITK 8     // K-split for skinny MFMA gemms

__device__ __forceinline__ float b2f(bf16 x) { return __bfloat162float(x); }
__device__ __forceinline__ bf16  f2b(float x) { return __float2bfloat16(x); }

// ---------------------------------------------------------------------------
// K0: fp32 -> bf16 weight conversion (for MFMA GEMMs)
// ---------------------------------------------------------------------------
__global__ __launch_bounds__(256) void cvt_kernel(
    const float* __restrict__ in, bf16* __restrict__ out)
{
  int i = blockIdx.x * 256 + threadIdx.x;
  out[i] = f2b(in[i]);
}

// ---------------------------------------------------------------------------
// K0b: fp32 [K,N] -> bf16 hi/lo [N,K] transpose-convert (K == 2048 fixed).
// hi = bf16(w); lo = bf16(w - hi). Two-MFMA accumulation recovers ~fp32 B.
// ---------------------------------------------------------------------------
__global__ __launch_bounds__(256) void cvt_t2_kernel(
    const float* __restrict__ in, bf16* __restrict__ hi, bf16* __restrict__ lo,
    int N)
{
  int idx = blockIdx.x * 256 + threadIdx.x;   // over N*2048
  int n = idx >> 11, k = idx & 2047;
  float v = in[(size_t)k * N + n];
  bf16 h = f2b(v);
  hi[idx] = h;
  lo[idx] = f2b(v - b2f(h));
}

// ---------------------------------------------------------------------------
// K0c: w2 fp32 [160, C] -> bf16 hi/lo [C, 160] transpose-convert.
// ---------------------------------------------------------------------------
__global__ __launch_bounds__(256) void cvt_w2t_kernel(
    const float* __restrict__ in, bf16* __restrict__ hi, bf16* __restrict__ lo)
{
  int idx = blockIdx.x * 256 + threadIdx.x;   // over 2048*160
  int c = idx / 160, e = idx - c * 160;
  float v = in[(size_t)e * Cc + c];
  bf16 h = f2b(v);
  hi[idx] = h;
  lo[idx] = f2b(v - b2f(h));
}

// ---------------------------------------------------------------------------
// K1: xm = x + (shift(x) - x) * time_maa_x
// ---------------------------------------------------------------------------
__global__ __launch_bounds__(256) void prep_xm_kernel(
    const float* __restrict__ x, const float* __restrict__ maa_x,
    bf16* __restrict__ xm)
{
  int idx = blockIdx.x * 256 + threadIdx.x;
  int c  = idx & (Cc - 1);
  int bt = idx >> 11;
  int t  = bt & (Tt - 1);
  float xv   = x[idx];
  float prev = (t == 0) ? 0.f : x[idx - Cc];
  xm[idx] = f2b(xv + (prev - xv) * maa_x[c]);
}

// ---------------------------------------------------------------------------
// MFMA GEMM: C[8192,2048] = A[8192,2048](bf16) * B^T, B[2048,2048](bf16,[N,K])
// 128x128 block tile, 4 waves in 2x2, each wave 64x64 via 4x4 16x16x32 MFMAs.
// mode: 0 plain->bf16, 2 silu->bf16, 4 plain->fp32
// ---------------------------------------------------------------------------
#define LDA 40   // padded LDS row (bf16 elems): 20 dwords -> ~2-way conflicts

__global__ __launch_bounds__(256) void mfma_gemm_kernel(
    const bf16* __restrict__ A, const bf16* __restrict__ B,
    bf16* __restrict__ outB, float* __restrict__ outF, int mode)
{
  __shared__ bf16 As[128 * LDA];
  __shared__ bf16 Bs[128 * LDA];
  int tid  = threadIdx.x;
  int lane = tid & 63, wid = tid >> 6;
  int wm = wid & 1, wn = wid >> 1;
  int quad = lane >> 4, l16 = lane & 15;
  size_t rowBase = (size_t)blockIdx.x * 128;
  size_t colBase = (size_t)blockIdx.y * 128;

  f32x4 acc[4][4];
  #pragma unroll
  for (int i = 0; i < 4; ++i)
    #pragma unroll
    for (int j = 0; j < 4; ++j)
      acc[i][j] = (f32x4){0.f, 0.f, 0.f, 0.f};

  for (int k0 = 0; k0 < 2048; k0 += 32) {
    #pragma unroll
    for (int pass = 0; pass < 2; ++pass) {
      int chunk = tid + pass * 256;           // 0..511
      int row = chunk >> 2, kc = (chunk & 3) * 8;
      short8 av = *(const short8*)(A + (rowBase + row) * 2048 + k0 + kc);
      short8 bv = *(const short8*)(B + (colBase + row) * 2048 + k0 + kc);
      *(short8*)(As + row * LDA + kc) = av;
      *(short8*)(Bs + row * LDA + kc) = bv;
    }
    __syncthreads();
    short8 af[4], bf[4];
    #pragma unroll
    for (int i = 0; i < 4; ++i) {
      af[i] = *(const short8*)(As + (wm * 64 + i * 16 + l16) * LDA + quad * 8);
      bf[i] = *(const short8*)(Bs + (wn * 64 + i * 16 + l16) * LDA + quad * 8);
    }
    #pragma unroll
    for (int i = 0; i < 4; ++i)
      #pragma unroll
      for (int j = 0; j < 4; ++j)
        acc[i][j] = __builtin_amdgcn_mfma_f32_16x16x32_bf16(af[i], bf[j], acc[i][j], 0, 0, 0);
    __syncthreads();
  }

  #pragma unroll
  for (int i = 0; i < 4; ++i) {
    #pragma unroll
    for (int j = 0; j < 4; ++j) {
      int gc = colBase + wn * 64 + j * 16 + l16;
      #pragma unroll
      for (int reg = 0; reg < 4; ++reg) {
        int gr = rowBase + wm * 64 + i * 16 + quad * 4 + reg;
        float v = acc[i][j][reg];
        size_t idx = (size_t)gr * 2048 + gc;
        if (mode == 0)      outB[idx] = f2b(v);
        else if (mode == 2) outB[idx] = f2b(v / (1.f + expf(-v)));
        else                outF[idx] = v;
      }
    }
  }
}

// ---------------------------------------------------------------------------
// Skinny MFMA GEMM with split-K and hi/lo B compensation:
// C_partial[kseg][8192][N] = A_seg @ (Bhi+Blo)_seg^T.
// ---------------------------------------------------------------------------
template<int NF>
__global__ __launch_bounds__(256) void mfma_skinny_kernel(
    const bf16* __restrict__ A, const bf16* __restrict__ Bt_hi,
    const bf16* __restrict__ Bt_lo,
    float* __restrict__ partial, int kseg_len)
{
  constexpr int N = NF * 16;
  __shared__ bf16 As[64 * LDA];
  __shared__ bf16 Bs[2 * N * LDA];   // rows 0..N-1 hi, N..2N-1 lo
  int tid = threadIdx.x;
  int lane = tid & 63, w = tid >> 6;
  int quad = lane >> 4, l16 = lane & 15;
  int rowBase = blockIdx.x * 64;
  int kbeg = blockIdx.y * kseg_len;

  f32x4 acc[NF];
  #pragma unroll
  for (int f = 0; f < NF; ++f) acc[f] = (f32x4){0.f, 0.f, 0.f, 0.f};

  for (int k0 = kbeg; k0 < kbeg + kseg_len; k0 += 32) {
    // stage A 64x32 (256 threads x 8 elems)
    {
      int row = tid >> 2, kc = (tid & 3) * 8;
      *(short8*)(As + row * LDA + kc) =
          *(const short8*)(A + (size_t)(rowBase + row) * 2048 + k0 + kc);
    }
    // stage B hi and lo, N x 32 each
    for (int c = tid; c < N * 8; c += 256) {
      int half = c >= N * 4;
      int cc = c - half * N * 4;
      int row = cc >> 2, kc = (cc & 3) * 8;
      const bf16* src = half ? Bt_lo : Bt_hi;
      *(short8*)(Bs + (half * N + row) * LDA + kc) =
          *(const short8*)(src + (size_t)row * 2048 + k0 + kc);
    }
    __syncthreads();
    short8 af = *(const short8*)(As + (w * 16 + l16) * LDA + quad * 8);
    #pragma unroll
    for (int f = 0; f < NF; ++f) {
      short8 bh = *(const short8*)(Bs + (f * 16 + l16) * LDA + quad * 8);
      short8 bl = *(const short8*)(Bs + ((N + f * 16 + l16)) * LDA + quad * 8);
      acc[f] = __builtin_amdgcn_mfma_f32_16x16x32_bf16(af, bh, acc[f], 0, 0, 0);
      acc[f] = __builtin_amdgcn_mfma_f32_16x16x32_bf16(af, bl, acc[f], 0, 0, 0);
    }
    __syncthreads();
  }

  #pragma unroll
  for (int f = 0; f < NF; ++f) {
    int gc = f * 16 + l16;
    #pragma unroll
    for (int reg = 0; reg < 4; ++reg) {
      int gr = rowBase + w * 16 + quad * 4 + reg;
      partial[((size_t)blockIdx.y * 8192 + gr) * N + gc] = acc[f][reg];
    }
  }
}

// sum SPLITK partials + tanh -> bf16
__global__ __launch_bounds__(256) void reduce_tanh_kernel(
    const float* __restrict__ partial, bf16* __restrict__ out, int MN)
{
  int idx = blockIdx.x * 256 + threadIdx.x;
  float s = 0.f;
  #pragma unroll
  for (int j = 0; j < SPLITK; ++j) s += partial[(size_t)j * MN + idx];
  out[idx] = f2b(tanhf(s));
}

// ---------------------------------------------------------------------------
// VALU tiled GEMM (still used for td: M=8192,N=2048,K=64). A bf16, B fp32.
// mode: 1 tanh->bf16, 3 td = bias[n]+acc -> bf16
// ---------------------------------------------------------------------------
#define BM 128
#define BN 128
#define BKk 16

__global__ __launch_bounds__(256) void gemm_kernel(
    const bf16* __restrict__ A, const float* __restrict__ Bm,
    bf16* __restrict__ outB,
    const float* __restrict__ bias,
    int M, int N, int K, int transB, int mode)
{
  __shared__ float As[BKk][BM + 1];
  __shared__ float Bs[BKk][BN + 1];
  int tid = threadIdx.x;
  int rowBase = blockIdx.x * BM;
  int colBase = blockIdx.y * BN;
  int tx = tid & 15, ty = tid >> 4;
  float acc[8][8];
  #pragma unroll
  for (int i = 0; i < 8; ++i)
    #pragma unroll
    for (int j = 0; j < 8; ++j) acc[i][j] = 0.f;

  for (int k0 = 0; k0 < K; k0 += BKk) {
    #pragma unroll
    for (int i = 0; i < 8; ++i) {
      int lin = tid + i * 256;
      int r = lin >> 4, kk = lin & 15;
      int gr = rowBase + r, gk = k0 + kk;
      float val = 0.f;
      if (gr < M && gk < K) val = b2f(A[(size_t)gr * K + gk]);
      As[kk][r] = val;
    }
    #pragma unroll
    for (int i = 0; i < 8; ++i) {
      int lin = tid + i * 256;
      float val = 0.f;
      if (transB) {
        int n = lin >> 4, kk = lin & 15;
        int gn = colBase + n, gk = k0 + kk;
        if (gn < N && gk < K) val = Bm[(size_t)gn * K + gk];
        Bs[kk][n] = val;
      } else {
        int kk = lin >> 7, n = lin & 127;
        int gn = colBase + n, gk = k0 + kk;
        if (gn < N && gk < K) val = Bm[(size_t)gk * N + gn];
        Bs[kk][n] = val;
      }
    }
    __syncthreads();
    #pragma unroll
    for (int kk = 0; kk < BKk; ++kk) {
      float a[8], b[8];
      #pragma unroll
      for (int i = 0; i < 8; ++i) a[i] = As[kk][ty * 8 + i];
      #pragma unroll
      for (int j = 0; j < 8; ++j) b[j] = Bs[kk][tx * 8 + j];
      #pragma unroll
      for (int i = 0; i < 8; ++i)
        #pragma unroll
        for (int j = 0; j < 8; ++j)
          acc[i][j] = fmaf(a[i], b[j], acc[i][j]);
    }
    __syncthreads();
  }
  #pragma unroll
  for (int i = 0; i < 8; ++i) {
    int gr = rowBase + ty * 8 + i;
    if (gr >= M) continue;
    #pragma unroll
    for (int j = 0; j < 8; ++j) {
      int gn = colBase + tx * 8 + j;
      if (gn >= N) continue;
      float v = acc[i][j];
      size_t idx = (size_t)gr * N + gn;
      if (mode == 1)      outB[idx] = f2b(tanhf(v));
      else                outB[idx] = f2b(bias[gn] + v);   // mode 3
    }
  }
}

// ---------------------------------------------------------------------------
// K3: fused 5-way token-shift lerp via MFMA. For each f in 0..4:
// m_f[128x128 tile] = t5[:, f*32:(f+1)*32] @ w2t_f^T (hi/lo compensated),
// then out_f = x + (shift(x)-x) * (maa_f + m_f). K=32 -> fragments loaded
// directly from global (t5/w2t are L2-resident); no LDS, no barriers.
// Same fragment maps as mfma_gemm_kernel. Grid (64,16), 4 waves 2x2.
// ---------------------------------------------------------------------------
__global__ __launch_bounds__(256) void lerp5_mfma_kernel(
    const float* __restrict__ x, const bf16* __restrict__ t5,
    const bf16* __restrict__ w2t_hi, const bf16* __restrict__ w2t_lo,
    const float* __restrict__ maa_w, const float* __restrict__ maa_k,
    const float* __restrict__ maa_v, const float* __restrict__ maa_r,
    const float* __restrict__ maa_g,
    bf16* __restrict__ xd, bf16* __restrict__ xk, bf16* __restrict__ xv_,
    bf16* __restrict__ xr, bf16* __restrict__ xg)
{
  int tid  = threadIdx.x;
  int lane = tid & 63, wid = tid >> 6;
  int wm = wid & 1, wn = wid >> 1;
  int quad = lane >> 4, l16 = lane & 15;
  int rowBase = blockIdx.x * 128;
  int colBase = blockIdx.y * 128;

  const float* maas[5] = {maa_w, maa_k, maa_v, maa_r, maa_g};
  bf16* outs[5] = {xd, xk, xv_, xr, xg};

  #pragma unroll
  for (int f = 0; f < 5; ++f) {
    // A fragments: t5[row][f*32 + quad*8 .. +8]
    short8 af[4];
    #pragma unroll
    for (int i = 0; i < 4; ++i)
      af[i] = *(const short8*)(t5 +
          (size_t)(rowBase + wm * 64 + i * 16 + l16) * 160 + f * 32 + quad * 8);

    f32x4 acc[4][4];
    #pragma unroll
    for (int i = 0; i < 4; ++i)
      #pragma unroll
      for (int j = 0; j < 4; ++j)
        acc[i][j] = (f32x4){0.f, 0.f, 0.f, 0.f};

    #pragma unroll
    for (int j = 0; j < 4; ++j) {
      size_t boff = (size_t)(colBase + wn * 64 + j * 16 + l16) * 160 + f * 32 + quad * 8;
      short8 bh = *(const short8*)(w2t_hi + boff);
      short8 bl = *(const short8*)(w2t_lo + boff);
      #pragma unroll
      for (int i = 0; i < 4; ++i) {
        acc[i][j] = __builtin_amdgcn_mfma_f32_16x16x32_bf16(af[i], bh, acc[i][j], 0, 0, 0);
        acc[i][j] = __builtin_amdgcn_mfma_f32_16x16x32_bf16(af[i], bl, acc[i][j], 0, 0, 0);
      }
    }

    const float* maa = maas[f];
    bf16* outp = outs[f];
    #pragma unroll
    for (int j = 0; j < 4; ++j) {
      int gc = colBase + wn * 64 + j * 16 + l16;
      float mv = maa[gc];
      #pragma unroll
      for (int i = 0; i < 4; ++i) {
        #pragma unroll
        for (int reg = 0; reg < 4; ++reg) {
          int gr = rowBase + wm * 64 + i * 16 + quad * 4 + reg;
          size_t idx = (size_t)gr * Cc + gc;
          float xv0  = x[idx];
          float prev = ((gr & (Tt - 1)) == 0) ? 0.f : x[idx - Cc];
          outp[idx] = f2b(xv0 + (prev - xv0) * (mv + acc[i][j][reg]));
        }
      }
    }
  }
}

// ---------------------------------------------------------------------------
// K5a: chunked WKV local scan. Grid = B*H*G.
// ---------------------------------------------------------------------------
__global__ __launch_bounds__(256) void wkv_local_kernel(
    const bf16* __restrict__ k, const bf16* __restrict__ v,
    const bf16* __restrict__ td,
    float* __restrict__ S_local, float* __restrict__ wp)
{
  int bh = blockIdx.x >> 4;          // Gg == 16
  int c  = blockIdx.x & 15;
  int b  = bh >> 5, h = bh & 31;
  int tid = threadIdx.x;
  int m = tid & 63, chunk = tid >> 6;
  __shared__ float kw[2][64][2];     // [buf][ch][{k,w}]
  __shared__ float vsb[2][64];
  float s[16], wpr[16];
  #pragma unroll
  for (int i = 0; i < 16; ++i) { s[i] = 0.f; wpr[i] = 1.f; }
  size_t base = (size_t)b * Tt * Cc + (size_t)(c * Ll) * Cc + (size_t)h * 64;
  for (int t = 0; t < Ll; ++t, base += Cc) {
    int p = t & 1;
    int role = tid >> 6, ch = tid & 63;
    if (role == 0)      kw[p][ch][0] = b2f(k[base + ch]);
    else if (role == 1) kw[p][ch][1] = expf(-expf(b2f(td[base + ch])));
    else if (role == 2) vsb[p][ch]   = b2f(v[base + ch]);
    __syncthreads();
    float vm = vsb[p][m];
    #pragma unroll
    for (int i = 0; i < 16; ++i) {
      float kk = kw[p][chunk * 16 + i][0];
      float ww = kw[p][chunk * 16 + i][1];
      s[i] = fmaf(ww, s[i], kk * vm);
      wpr[i] *= ww;
    }
  }
  size_t sb = ((size_t)blockIdx.x * 64 + chunk * 16) * 64 + m;
  #pragma unroll
  for (int i = 0; i < 16; ++i) S_local[sb + (size_t)i * 64] = s[i];
  if (m == 0) {
    int wb = blockIdx.x * 64 + chunk * 16;
    #pragma unroll
    for (int i = 0; i < 16; ++i) wp[wb + i] = wpr[i];
  }
}

// ---------------------------------------------------------------------------
// K5b: chunk-prefix combine over Gg=16 chunks, parallel over (b,h,n,m).
// ---------------------------------------------------------------------------
__global__ __launch_bounds__(256) void wkv_combine_kernel(
    const float* __restrict__ S_local, const float* __restrict__ wp,
    float* __restrict__ S_start)
{
  int idx = blockIdx.x * 256 + threadIdx.x;   // over B*H*N*N
  int m = idx & 63;
  int n = (idx >> 6) & 63;
  int bh = idx >> 12;
  float cur = 0.f;
  #pragma unroll
  for (int c = 0; c < Gg; ++c) {
    size_t sbase = (((size_t)(bh * Gg + c)) * 64 + n) * 64 + m;
    S_start[sbase] = cur;
    cur = fmaf(wp[(bh * Gg + c) * 64 + n], cur, S_local[sbase]);
  }
}

// ---------------------------------------------------------------------------
// K5c: chunked WKV output scan, seeded from S_start; writes in place over td.
// ---------------------------------------------------------------------------
__global__ __launch_bounds__(256) void wkv_out_kernel(
    const bf16* __restrict__ r, const bf16* __restrict__ k,
    const bf16* __restrict__ v, const bf16* __restrict__ td,
    const float* __restrict__ u, const float* __restrict__ S_start,
    bf16* __restrict__ out)
{
  int bh = blockIdx.x >> 4;
  int c  = blockIdx.x & 15;
  int b  = bh >> 5, h = bh & 31;
  int tid = threadIdx.x;
  int m = tid & 63, chunk = tid >> 6;
  __shared__ float4 rkw[64];
  __shared__ float vsb[64];
  __shared__ float red[256];
  float s[16], ureg[16];
  size_t sb = ((size_t)blockIdx.x * 64 + chunk * 16) * 64 + m;
  #pragma unroll
  for (int i = 0; i < 16; ++i) {
    s[i]    = S_start[sb + (size_t)i * 64];
    ureg[i] = u[h * 64 + chunk * 16 + i];
  }
  size_t base = (size_t)b * Tt * Cc + (size_t)(c * Ll) * Cc + (size_t)h * 64;
  for (int t = 0; t < Ll; ++t, base += Cc) {
    int role = tid >> 6, ch = tid & 63;
    if (role == 0)      rkw[ch].x = b2f(r[base + ch]);
    else if (role == 1) rkw[ch].y = b2f(k[base + ch]);
    else if (role == 2) rkw[ch].z = expf(-expf(b2f(td[base + ch])));
    else                vsb[ch]   = b2f(v[base + ch]);
    __syncthreads();
    float vm = vsb[m];
    float acc = 0.f;
    #pragma unroll
    for (int i = 0; i < 16; ++i) {
      float4 q = rkw[chunk * 16 + i];
      float kv = q.y * vm;
      acc = fmaf(q.x, fmaf(ureg[i], kv, s[i]), acc);
      s[i] = fmaf(q.z, s[i], kv);
    }
    red[tid] = acc;
    __syncthreads();
    if (tid < 64)
      out[base + tid] = f2b(red[tid] + red[tid + 64] + red[tid + 128] + red[tid + 192]);
  }
}

// ---------------------------------------------------------------------------
// K6: GroupNorm over each head (N=64) + affine + gate with g
// ---------------------------------------------------------------------------
__global__ __launch_bounds__(256) void gn_gate_kernel(
    const bf16* __restrict__ wkv, const bf16* __restrict__ g,
    const float* __restrict__ lnw, const float* __restrict__ lnb,
    bf16* __restrict__ out)
{
  int bt = blockIdx.x;
  int wv = threadIdx.x >> 6, lane = threadIdx.x & 63;
  const float EPS = 6.4e-4f;   // 1e-5 * 8^2
  for (int h = wv; h < Hh; h += 4) {
    size_t base = (size_t)bt * Cc + h * 64;
    float x = b2f(wkv[base + lane]);
    float s = x, s2 = x * x;
    #pragma unroll
    for (int off = 1; off < 64; off <<= 1) {
      s  += __shfl_xor(s, off);
      s2 += __shfl_xor(s2, off);
    }
    float mean = s * (1.f / 64.f);
    float var  = s2 * (1.f / 64.f) - mean * mean;
    float inv  = rsqrtf(var + EPS);
    float normed = (x - mean) * inv * lnw[h * 64 + lane] + lnb[h * 64 + lane];
    out[base + lane] = f2b(normed * b2f(g[base + lane]));
  }
}

// ---------------------------------------------------------------------------
// Workspace map: 5 x 33.55 MB bf16 [BT,C] + 8 MB small-region + 5 x 8.39 MB
// bf16 weights ~= 218 MB. Small-region layout (offsets from ws+5*BUF):
//   +0      t5buf (2.5 MB bf16), doubles as wp (512 KB fp32) at scan time
//   +4 MB   abuf (1 MB bf16)
//   +5 MB   w1t_hi (640 KB), +5.75 MB w1t_lo (640 KB)
//   +6.5 MB dw1t_hi (256 KB), +6.75 MB dw1t_lo (256 KB)
// d_out (67 MB): bytes 0..42 MB = skinny-gemm fp32 partials (stages 2,4);
// bytes 48..49.3 MB = w2t hi/lo (consumed at stage 3); then lower half =
// bf16 r-scratch + upper half = S_local (stage 5+). S_start reuses buf0.
// ---------------------------------------------------------------------------
extern "C" void kernel_launch(void* const* d_in, const int* in_sizes, int n_in,
                              void* d_out, int out_size, void* d_ws, size_t ws_size,
                              hipStream_t stream) {
  const float* hidden = (const float*)d_in[0];
  const float* maa_x  = (const float*)d_in[1];
  const float* maa_w  = (const float*)d_in[2];
  const float* maa_k  = (const float*)d_in[3];
  const float* maa_v  = (const float*)d_in[4];
  const float* maa_r  = (const float*)d_in[5];
  const float* maa_g  = (const float*)d_in[6];
  const float* maa_w1 = (const float*)d_in[7];   // [C,160]
  const float* maa_w2 = (const float*)d_in[8];   // [160,C]
  const float* tdecay = (const float*)d_in[9];   // [C]
  const float* dw1    = (const float*)d_in[10];  // [C,64]
  const float* dw2    = (const float*)d_in[11];  // [64,C]
  const float* faaaa  = (const float*)d_in[12];  // [H,N]
  const float* w_r    = (const float*)d_in[13];
  const float* w_k    = (const float*)d_in[14];
  const float* w_v    = (const float*)d_in[15];
  const float* w_g    = (const float*)d_in[16];
  const float* w_o    = (const float*)d_in[17];
  const float* lnw    = (const float*)d_in[18];
  const float* lnb    = (const float*)d_in[19];
  float* outF = (float*)d_out;
  bf16* rscratch = (bf16*)d_out;

  char* ws = (char*)d_ws;
  const size_t BUF  = (size_t)BT * Cc * sizeof(bf16);   // 33,554,432 B
  const size_t WBUF = (size_t)Cc * Cc * sizeof(bf16);   //  8,388,608 B
  const size_t MB = 1024 * 1024;
  bf16* buf0 = (bf16*)(ws + 0 * BUF);
  bf16* buf1 = (bf16*)(ws + 1 * BUF);
  bf16* buf2 = (bf16*)(ws + 2 * BUF);
  bf16* buf3 = (bf16*)(ws + 3 * BUF);
  bf16* buf4 = (bf16*)(ws + 4 * BUF);
  char* small = ws + 5 * BUF;
  bf16* t5buf   = (bf16*)(small + 0);
  bf16* abuf    = (bf16*)(small + 4 * MB);
  bf16* w1t_hi  = (bf16*)(small + 5 * MB);
  bf16* w1t_lo  = (bf16*)(small + 5 * MB + 768 * 1024);
  bf16* dw1t_hi = (bf16*)(small + 6 * MB + 512 * 1024);
  bf16* dw1t_lo = (bf16*)(small + 6 * MB + 768 * 1024);
  char* wbase = small + 8 * MB;
  bf16* wrb = (bf16*)(wbase + 0 * WBUF);
  bf16* wkb = (bf16*)(wbase + 1 * WBUF);
  bf16* wvb = (bf16*)(wbase + 2 * WBUF);
  bf16* wgb = (bf16*)(wbase + 3 * WBUF);
  bf16* wob = (bf16*)(wbase + 4 * WBUF);

  // w2t hi/lo (640 KB each) live in d_out above the skinny partials
  bf16* w2t_hi = (bf16*)((char*)d_out + 48 * MB);
  bf16* w2t_lo = (bf16*)((char*)d_out + 49 * MB);

  // scan scratch: S_local in d_out upper half, S_start in buf0, wp in t5buf
  float* slbuf = (float*)((char*)d_out + BUF);   // 33.55 MB fp32
  float* ssbuf = (float*)buf0;                   // 33.55 MB fp32
  float* wpbuf = (float*)t5buf;                  // 512 KB fp32
  // skinny-gemm partial scratch: d_out bytes 0..42 MB (free until stage 5)
  float* pbuf  = (float*)d_out;

  dim3 blk(256);
  const int CVT_G = Cc * Cc / 256;   // 16384

  // 0. weight conversions (independent of data pipeline)
  cvt_kernel<<<dim3(CVT_G), blk, 0, stream>>>(w_r, wrb);
  cvt_kernel<<<dim3(CVT_G), blk, 0, stream>>>(w_k, wkb);
  cvt_kernel<<<dim3(CVT_G), blk, 0, stream>>>(w_v, wvb);
  cvt_kernel<<<dim3(CVT_G), blk, 0, stream>>>(w_g, wgb);
  cvt_kernel<<<dim3(CVT_G), blk, 0, stream>>>(w_o, wob);
  cvt_t2_kernel<<<dim3(160 * Cc / 256), blk, 0, stream>>>(maa_w1, w1t_hi, w1t_lo, 160);
  cvt_t2_kernel<<<dim3(64 * Cc / 256), blk, 0, stream>>>(dw1, dw1t_hi, dw1t_lo, 64);
  cvt_w2t_kernel<<<dim3(160 * Cc / 256), blk, 0, stream>>>(maa_w2, w2t_hi, w2t_lo);

  // 1. xm -> buf0
  prep_xm_kernel<<<dim3(BT * Cc / 256), blk, 0, stream>>>(hidden, maa_x, buf0);

  // 2. t5 = tanh(xm @ maa_w1): M=8192,N=160,K=2048 via split-K MFMA (hi/lo)
  mfma_skinny_kernel<10><<<dim3(128, SPLITK), blk, 0, stream>>>(
      buf0, w1t_hi, w1t_lo, pbuf, 2048 / SPLITK);
  reduce_tanh_kernel<<<dim3(BT * 160 / 256), blk, 0, stream>>>(pbuf, t5buf,
                                                               BT * 160);

  // 3. fused lerp (MFMA) -> xd(1) xk(2) xv(3) xr(4) xg(0)
  lerp5_mfma_kernel<<<dim3(64, 16), blk, 0, stream>>>(hidden, t5buf,
      w2t_hi, w2t_lo, maa_w, maa_k, maa_v, maa_r, maa_g,
      buf1, buf2, buf3, buf4, buf0);

  // 4. decay: a = tanh(xd @ dw1) [8192,64] via split-K MFMA (hi/lo);
  //    td = tdecay + a @ dw2 -> buf1 (VALU gemm, K=64)
  mfma_skinny_kernel<4><<<dim3(128, SPLITK), blk, 0, stream>>>(
      buf1, dw1t_hi, dw1t_lo, pbuf, 2048 / SPLITK);
  reduce_tanh_kernel<<<dim3(BT * 64 / 256), blk, 0, stream>>>(pbuf, abuf,
                                                              BT * 64);
  gemm_kernel<<<dim3(64, 16), blk, 0, stream>>>(abuf, dw2, buf1, tdecay,
                                                BT, Cc, 64, 0, 3);

  // 5. projections (MFMA): r->rscratch, k->buf4, v->buf2, g(silu)->buf3
  mfma_gemm_kernel<<<dim3(64, 16), blk, 0, stream>>>(buf4, wrb, rscratch, nullptr, 0);
  mfma_gemm_kernel<<<dim3(64, 16), blk, 0, stream>>>(buf2, wkb, buf4, nullptr, 0);
  mfma_gemm_kernel<<<dim3(64, 16), blk, 0, stream>>>(buf3, wvb, buf2, nullptr, 0);
  mfma_gemm_kernel<<<dim3(64, 16), blk, 0, stream>>>(buf0, wgb, buf3, nullptr, 2);

  // 6. chunked WKV scan: r=rscratch, k=buf4, v=buf2, td=buf1 -> out over buf1
  wkv_local_kernel<<<dim3(Bb * Hh * Gg), blk, 0, stream>>>(buf4, buf2, buf1,
                                                           slbuf, wpbuf);
  wkv_combine_kernel<<<dim3(Bb * Hh * Nn * Nn / 256), blk, 0, stream>>>(
      slbuf, wpbuf, ssbuf);
  wkv_out_kernel<<<dim3(Bb * Hh * Gg), blk, 0, stream>>>(rscratch, buf4, buf2,
      buf1, faaaa, ssbuf, buf1);

  // 7. GroupNorm + gate -> buf4 (wkv out now lives in buf1)
  gn_gate_kernel<<<dim3(BT), blk, 0, stream>>>(buf1, buf3, lnw, lnb, buf4);

  // 8. final projection (MFMA) -> d_out fp32
  mfma_gemm_kernel<<<dim3(64, 16), blk, 0, stream>>>(buf4, wob, nullptr, outF, 4);
}